// Round 6
// baseline (1997.313 us; speedup 1.0000x reference)
//
#include <hip/hip_runtime.h>

// Quantum-LSTM forward. Round-6 restructure: ONE WAVE PER SAMPLE, ZERO
// BARRIERS. Block=64 threads (1 wave), grid=512. Per t-step the wave runs
// the 4 phase-1 circuits as ILP-4 interleaved gate chains and the 2 phase-2
// circuits as ILP-2; cell state c, hidden h, and gate values never leave
// the wave (readlane / bpermute), so the t-loop has no __syncthreads and no
// LDS state traffic. Key algebraic fact (new): all phase-1 circuits share
// the same input X => ONE embedding serves all 4 (same for phase-2's pair).
// Gate coefficients are wave-uniform (SU(2) row-1 = conj-neg of row-0,
// R5-verified) and live in a 1.2 KB LDS table read via broadcast
// ds_read_b128. Shuffle masks on verified DPP where possible (R4/R5),
// ds_swizzle (<32) / ds_bpermute (>=32) otherwise -- all numerics identical
// to the R2-R5 passing kernels.

namespace {

constexpr int BATCH  = 512;
constexpr int TSTEPS = 256;

typedef float v2f __attribute__((ext_vector_type(2)));

__device__ __forceinline__ v2f splat2(float s) { v2f r; r.x = s; r.y = s; return r; }
__device__ __forceinline__ v2f cswapneg(v2f v) { v2f r; r.x = -v.y; r.y = v.x; return r; }

__device__ __forceinline__ float sigf(float v) { return 1.0f / (1.0f + __expf(-v)); }
__device__ __forceinline__ float tanh_fast(float v) { return 1.0f - 2.0f / (1.0f + __expf(v + v)); }

__device__ __forceinline__ float rl(float v, int l) {
  return __int_as_float(__builtin_amdgcn_readlane(__float_as_int(v), l));
}

template<int CTRL>
__device__ __forceinline__ float dppmov(float v) {
  return __int_as_float(__builtin_amdgcn_mov_dpp(__float_as_int(v), CTRL, 0xF, 0xF, true));
}
// Verified (R4/R5): quad_perm xor1=0xB1 xor2=0x4E xor3=0x1B; half_mirror=0x141
// (xor7), row_ror:8=0x128 (xor8), row_mirror=0x140 (xorF); composites 4,5,A,C.

template<int M>
__device__ __forceinline__ float shx(float v, int lane4) {
  if constexpr      (M == 0x01) return dppmov<0xB1>(v);
  else if constexpr (M == 0x02) return dppmov<0x4E>(v);
  else if constexpr (M == 0x03) return dppmov<0x1B>(v);
  else if constexpr (M == 0x04) return dppmov<0x1B>(dppmov<0x141>(v));
  else if constexpr (M == 0x05) return dppmov<0x4E>(dppmov<0x141>(v));
  else if constexpr (M == 0x07) return dppmov<0x141>(v);
  else if constexpr (M == 0x08) return dppmov<0x128>(v);
  else if constexpr (M == 0x0A) return dppmov<0x4E>(dppmov<0x128>(v));
  else if constexpr (M == 0x0C) return dppmov<0x1B>(dppmov<0x140>(v));
  else if constexpr (M == 0x0F) return dppmov<0x140>(v);
  else if constexpr (M < 32) {
    return __int_as_float(__builtin_amdgcn_ds_swizzle(__float_as_int(v), 0x1F | (M << 10)));
  } else {
    return __int_as_float(__builtin_amdgcn_ds_bpermute(lane4 ^ (M << 2), __float_as_int(v)));
  }
}

// one gate applied to N interleaved circuit states; coeffs from LDS broadcast
template<int M, int N>
__device__ __forceinline__ void gateN(v2f (&s)[N], const float4* __restrict__ Ks,
                                      int pm, int lane4) {
  float4 A[N];
#pragma unroll
  for (int c = 0; c < N; ++c) A[c] = Ks[c];
  v2f v[N];
#pragma unroll
  for (int c = 0; c < N; ++c) {
    v[c].x = shx<M>(s[c].x, lane4);
    v[c].y = shx<M>(s[c].y, lane4);
  }
#pragma unroll
  for (int c = 0; c < N; ++c) {
    float sai = __int_as_float(__float_as_int(A[c].y) ^ pm);
    float sbr = __int_as_float(__float_as_int(A[c].z) ^ pm);
    v2f u = splat2(A[c].x) * s[c];
    u = __builtin_elementwise_fma(splat2(sai), cswapneg(s[c]), u);
    u = __builtin_elementwise_fma(splat2(sbr), v[c],           u);
    u = __builtin_elementwise_fma(splat2(A[c].w), cswapneg(v[c]), u);
    s[c] = u;
  }
}

// 12-gate chain over N interleaved circuits; Kt layout [gate][circuit]
template<int N>
__device__ __forceinline__ void chainN(v2f (&s)[N], const float4* __restrict__ Kt,
                                       int base, const int (&pm)[12], int lane4) {
  gateN<0x0F, N>(s, Kt + 0*6  + base, pm[0],  lane4);
  gateN<0x1E, N>(s, Kt + 1*6  + base, pm[1],  lane4);
  gateN<0x3C, N>(s, Kt + 2*6  + base, pm[2],  lane4);
  gateN<0x3B, N>(s, Kt + 3*6  + base, pm[3],  lane4);
  gateN<0x3F, N>(s, Kt + 4*6  + base, pm[4],  lane4);
  gateN<0x3D, N>(s, Kt + 5*6  + base, pm[5],  lane4);
  gateN<0x16, N>(s, Kt + 6*6  + base, pm[6],  lane4);
  gateN<0x26, N>(s, Kt + 7*6  + base, pm[7],  lane4);
  gateN<0x05, N>(s, Kt + 8*6  + base, pm[8],  lane4);
  gateN<0x28, N>(s, Kt + 9*6  + base, pm[9],  lane4);
  gateN<0x14, N>(s, Kt + 10*6 + base, pm[10], lane4);
  gateN<0x0A, N>(s, Kt + 11*6 + base, pm[11], lane4);
}

// merged FWHT over N circuits + final indexed gather
template<int N>
__device__ __forceinline__ void expvalsN(const v2f (&s)[N], float (&Wv)[N],
                                         const float (&fs)[9], int lane4, int gaddr) {
  float p[N];
#pragma unroll
  for (int c = 0; c < N; ++c) p[c] = fmaf(s[c].x, s[c].x, s[c].y * s[c].y);
#pragma unroll
  for (int c = 0; c < N; ++c) {
    float pa = shx<1>(p[c], lane4), pb = shx<2>(p[c], lane4), pc = shx<3>(p[c], lane4);
    p[c] = fmaf(fs[0], p[c], fmaf(fs[1], pa, fmaf(fs[2], pb, pc)));
  }
#pragma unroll
  for (int c = 0; c < N; ++c) {
    float pa = shx<4>(p[c], lane4), pb = shx<8>(p[c], lane4), pc = shx<12>(p[c], lane4);
    p[c] = fmaf(fs[3], p[c], fmaf(fs[4], pa, fmaf(fs[5], pb, pc)));
  }
#pragma unroll
  for (int c = 0; c < N; ++c) {
    float pa = shx<16>(p[c], lane4), pb = shx<32>(p[c], lane4), pc = shx<48>(p[c], lane4);
    p[c] = fmaf(fs[6], p[c], fmaf(fs[7], pa, fmaf(fs[8], pb, pc)));
  }
#pragma unroll
  for (int c = 0; c < N; ++c)
    Wv[c] = __int_as_float(__builtin_amdgcn_ds_bpermute(gaddr, __float_as_int(p[c])));
}

// half-angle products for wire value Xv: A=c1c2 B=c1s2 C=s1c2 D=s1s2
__device__ __forceinline__ void trig(float Xv, float& A_, float& B_, float& C_, float& D_) {
  float tq   = Xv * Xv;
  float cth1 = rsqrtf(1.f + tq);
  float sth1 = Xv * cth1;
  float u1   = 1.f + cth1, r1 = rsqrtf(u1 + u1);
  float c1   = u1 * r1,    s1 = sth1 * r1;
  float tq2  = tq * tq;
  float cth2 = rsqrtf(1.f + tq2);
  float sth2 = tq * cth2;
  float u2   = 1.f + cth2, r2 = rsqrtf(u2 + u2);
  float c2   = u2 * r2,    s2 = sth2 * r2;
  A_ = c1 * c2; B_ = c1 * s2; C_ = s1 * c2; D_ = s1 * s2;
}

// product-state embedding via readlane broadcast (verified R2/R4/R5 form)
__device__ __forceinline__ v2f embed_rl(float A_, float B_, float C_, float D_, int lane) {
  float ar, ai;
  {
    float Aj = rl(A_,0), Bj = rl(B_,0), Cj = rl(C_,0), Dj = rl(D_,0);
    bool bj = lane & 1;
    ar = bj ? Cj : Aj;
    ai = bj ? Dj : -Bj;
  }
#pragma unroll
  for (int jj = 1; jj < 6; ++jj) {
    float Aj = rl(A_,jj), Bj = rl(B_,jj), Cj = rl(C_,jj), Dj = rl(D_,jj);
    bool bj = (lane >> jj) & 1;
    float fr = bj ? Cj : Aj;
    float fi = bj ? Dj : -Bj;
    float nr = ar * fr - ai * fi;
    ai = fmaf(ar, fi, ai * fr);
    ar = nr;
  }
  v2f s; s.x = ar; s.y = ai; return s;
}

#define PACK_IDX ((0x2AULL)|(0x15ULL<<6)|(0x01ULL<<12)|(0x35ULL<<18)|(0x3AULL<<24)|(0x3DULL<<30))

} // namespace

__global__ __launch_bounds__(64) __attribute__((amdgpu_waves_per_eu(1)))
void qlstm_kernel(const float* __restrict__ x, const float* __restrict__ phi,
                  const float* __restrict__ Wc, const float* __restrict__ bc,
                  float* __restrict__ out)
{
  __shared__ float4 Kt[72];   // [gate 0..11][circuit 0..5], row0 of fused SU(2)

  const int lane  = threadIdx.x & 63;
  const int lane4 = lane << 2;
  const int b     = blockIdx.x;

  // ---- one-time: fused gate row0 per (circuit g, gate rem) -> Kt[rem*6+g] ----
  for (int k = lane; k < 72; k += 64) {
    int g = k / 12, rem = k % 12, l = rem / 6, i = rem % 6;
    const float* w = phi + g*36 + l*18 + i*3;
    float sa, ca, sb, cb, sc, cc;
    sincosf(0.5f * w[0], &sa, &ca);
    sincosf(0.5f * w[1], &sb, &cb);
    sincosf(0.5f * w[2], &sc, &cc);
    float m00r =  cb*ca, m00i =  sb*sa;
    float m01r = -sb*ca, m01i = -cb*sa;
    float4 A;
    A.x = m00r*cc + m00i*sc;  A.y = m00i*cc - m00r*sc;
    A.z = m01r*cc + m01i*sc;  A.w = m01i*cc - m01r*sc;
    Kt[rem*6 + g] = A;
  }
  __syncthreads();   // single wave: cheap; orders LDS init

  // ---- per-lane loop-invariants ----
  const int j = (lane < 6) ? lane : 0;           // owned wire
  float Wr[14];
#pragma unroll
  for (int k = 0; k < 14; ++k) Wr[k] = Wc[j*14 + k];
  const float bcj = bc[j];

  float sgn[6];
#pragma unroll
  for (int k = 0; k < 6; ++k) sgn[k] = ((lane >> k) & 1) ? -1.f : 1.f;
  float fs[9] = { sgn[0]*sgn[1], sgn[1], sgn[0],
                  sgn[2]*sgn[3], sgn[3], sgn[2],
                  sgn[4]*sgn[5], sgn[5], sgn[4] };

  int sh    = (lane < 6) ? (6 * lane) : 0;
  int gaddr = (int)((PACK_IDX >> sh) & 63ULL) << 2;

  constexpr unsigned BM[2][6] = {
    {0x18,0x30,0x39,0x0C,0x26,0x33},
    {0x2A,0x15,0x01,0x35,0x3A,0x3D}};
  int pm[12];
#pragma unroll
  for (int l = 0; l < 2; ++l)
#pragma unroll
    for (int i = 0; i < 6; ++i)
      pm[l*6+i] = (__popc(lane & (int)BM[l][i]) & 1) << 31;

  float c_sc = 0.f;   // lane i (<6) owns c_i
  float hreg = 0.f;   // lane i (<6) owns h_i

  const float* xbase = x + (size_t)b * TSTEPS * 8;
  float4 xa = *(const float4*)(xbase);
  float4 xb = *(const float4*)(xbase + 4);

  for (int t = 0; t < TSTEPS; ++t) {
    // ---- X_j in lane j (h via readlane; no cross-wave traffic) ----
    float h0 = rl(hreg,0), h1 = rl(hreg,1), h2 = rl(hreg,2);
    float h3 = rl(hreg,3), h4 = rl(hreg,4), h5 = rl(hreg,5);
    float acc = bcj;
    acc = fmaf(xa.x, Wr[0],  acc); acc = fmaf(xa.y, Wr[1],  acc);
    acc = fmaf(xa.z, Wr[2],  acc); acc = fmaf(xa.w, Wr[3],  acc);
    acc = fmaf(xb.x, Wr[4],  acc); acc = fmaf(xb.y, Wr[5],  acc);
    acc = fmaf(xb.z, Wr[6],  acc); acc = fmaf(xb.w, Wr[7],  acc);
    acc = fmaf(h0,   Wr[8],  acc); acc = fmaf(h1,   Wr[9],  acc);
    acc = fmaf(h2,   Wr[10], acc); acc = fmaf(h3,   Wr[11], acc);
    acc = fmaf(h4,   Wr[12], acc); acc = fmaf(h5,   Wr[13], acc);
    float Xj = 1.f - 2.f / (1.f + __expf(acc));

    // prefetch next x (in flight across the whole step)
    int tn = (t + 1 < TSTEPS) ? (t + 1) : t;
    float4 xa_n = *(const float4*)(xbase + (size_t)tn * 8);
    float4 xb_n = *(const float4*)(xbase + (size_t)tn * 8 + 4);

    // ---- phase 1: ONE embed, 4 interleaved circuits (f,i,C,o) ----
    float A_, B_, C_, D_;
    trig(Xj, A_, B_, C_, D_);
    v2f e = embed_rl(A_, B_, C_, D_, lane);
    v2f s4[4] = { e, e, e, e };
    chainN<4>(s4, Kt, 0, pm, lane4);
    float Wv[4];
    expvalsN<4>(s4, Wv, fs, lane4, gaddr);

    // ---- cell update (per-lane, lanes 0-5 meaningful) ----
    float fg = sigf(Wv[0]), ig = sigf(Wv[1]);
    float Cg = sigf(Wv[2]), og = sigf(Wv[3]);
    float cn = fmaf(fg, c_sc, ig * Cg);
    c_sc = cn;
    float resc = og * tanh_fast(cn);

    // ---- phase 2: ONE embed, 2 interleaved circuits (h, y) ----
    float A2, B2, C2, D2;
    trig(resc, A2, B2, C2, D2);
    v2f e2 = embed_rl(A2, B2, C2, D2, lane);
    v2f s2[2] = { e2, e2 };
    chainN<2>(s2, Kt, 4, pm, lane4);
    float Wv2[2];
    expvalsN<2>(s2, Wv2, fs, lane4, gaddr);

    hreg = Wv2[0];
    if (lane < 6) out[((size_t)b * TSTEPS + t) * 6 + lane] = Wv2[1];

    xa = xa_n; xb = xb_n;
  }

  // ---- final c, h ----
  if (lane < 6) {
    size_t cbase = (size_t)BATCH * TSTEPS * 6;
    out[cbase + (size_t)b * 6 + lane] = c_sc;
    out[cbase + (size_t)BATCH * 6 + (size_t)b * 6 + lane] = hreg;
  }
}

extern "C" void kernel_launch(void* const* d_in, const int* in_sizes, int n_in,
                              void* d_out, int out_size, void* d_ws, size_t ws_size,
                              hipStream_t stream) {
  const float* x   = (const float*)d_in[0];
  const float* phi = (const float*)d_in[1];
  const float* Wc  = (const float*)d_in[2];
  const float* bc  = (const float*)d_in[3];
  float* out = (float*)d_out;
  (void)in_sizes; (void)n_in; (void)out_size; (void)d_ws; (void)ws_size;
  hipLaunchKernelGGL(qlstm_kernel, dim3(BATCH), dim3(64), 0, stream,
                     x, phi, Wc, bc, out);
}

// Round 7
// 1182.904 us; speedup vs baseline: 1.6885x; 1.6885x over previous
//
#include <hip/hip_runtime.h>

// Quantum-LSTM forward. Round-7: barrier-free single-wave design (R6) with
// the spill root-cause fixed. R6's counters (WRITE_SIZE 3->27 MB, VGPR=256)
// showed LICM hoisted all 72 loop-invariant LDS coefficient loads into
// registers and spilled to scratch. Fix: coefficients move to the SCALAR
// path -- a prep kernel fuses RZ*RY*RX row-0 into d_ws, the main kernel
// reads them as wave-uniform s_load_dwordx4 (zero DS ops, zero VGPR cost),
// with an asm "+s" pin on the pointer per iteration to defeat LICM.
// Everything else (GF(2) masks, DPP set, embed, FWHT, ILP-4/ILP-2 chains)
// is the R6 structure whose numerics passed.

namespace {

constexpr int BATCH  = 512;
constexpr int TSTEPS = 256;

typedef float v2f __attribute__((ext_vector_type(2)));

__device__ __forceinline__ v2f splat2(float s) { v2f r; r.x = s; r.y = s; return r; }
__device__ __forceinline__ v2f cswapneg(v2f v) { v2f r; r.x = -v.y; r.y = v.x; return r; }

__device__ __forceinline__ float sigf(float v) { return 1.0f / (1.0f + __expf(-v)); }
__device__ __forceinline__ float tanh_fast(float v) { return 1.0f - 2.0f / (1.0f + __expf(v + v)); }

__device__ __forceinline__ float rl(float v, int l) {
  return __int_as_float(__builtin_amdgcn_readlane(__float_as_int(v), l));
}

template<int CTRL>
__device__ __forceinline__ float dppmov(float v) {
  return __int_as_float(__builtin_amdgcn_mov_dpp(__float_as_int(v), CTRL, 0xF, 0xF, true));
}
// Verified (R4-R6): quad_perm xor1=0xB1 xor2=0x4E xor3=0x1B; half_mirror=0x141
// (xor7), row_ror:8=0x128 (xor8), row_mirror=0x140 (xorF); composites 4,5,A,C.

template<int M>
__device__ __forceinline__ float shx(float v, int lane4) {
  if constexpr      (M == 0x01) return dppmov<0xB1>(v);
  else if constexpr (M == 0x02) return dppmov<0x4E>(v);
  else if constexpr (M == 0x03) return dppmov<0x1B>(v);
  else if constexpr (M == 0x04) return dppmov<0x1B>(dppmov<0x141>(v));
  else if constexpr (M == 0x05) return dppmov<0x4E>(dppmov<0x141>(v));
  else if constexpr (M == 0x07) return dppmov<0x141>(v);
  else if constexpr (M == 0x08) return dppmov<0x128>(v);
  else if constexpr (M == 0x0A) return dppmov<0x4E>(dppmov<0x128>(v));
  else if constexpr (M == 0x0C) return dppmov<0x1B>(dppmov<0x140>(v));
  else if constexpr (M == 0x0F) return dppmov<0x140>(v);
  else if constexpr (M < 32) {
    return __int_as_float(__builtin_amdgcn_ds_swizzle(__float_as_int(v), 0x1F | (M << 10)));
  } else {
    return __int_as_float(__builtin_amdgcn_ds_bpermute(lane4 ^ (M << 2), __float_as_int(v)));
  }
}

// one gate over N interleaved circuit states; coeffs via uniform scalar loads
template<int M, int N>
__device__ __forceinline__ void gateN(v2f (&s)[N], const float4* __restrict__ Kg,
                                      int pm, int lane4) {
  float4 A[N];
#pragma unroll
  for (int c = 0; c < N; ++c) A[c] = Kg[c];   // uniform -> s_load_dwordx4
  v2f v[N];
#pragma unroll
  for (int c = 0; c < N; ++c) {
    v[c].x = shx<M>(s[c].x, lane4);
    v[c].y = shx<M>(s[c].y, lane4);
  }
#pragma unroll
  for (int c = 0; c < N; ++c) {
    float sai = __int_as_float(__float_as_int(A[c].y) ^ pm);
    float sbr = __int_as_float(__float_as_int(A[c].z) ^ pm);
    v2f u = splat2(A[c].x) * s[c];
    u = __builtin_elementwise_fma(splat2(sai), cswapneg(s[c]), u);
    u = __builtin_elementwise_fma(splat2(sbr), v[c],           u);
    u = __builtin_elementwise_fma(splat2(A[c].w), cswapneg(v[c]), u);
    s[c] = u;
  }
}

// 12-gate chain over N interleaved circuits; K layout [gate][circuit 0..5]
template<int N>
__device__ __forceinline__ void chainN(v2f (&s)[N], const float4* __restrict__ K,
                                       int base, const int (&pm)[12], int lane4) {
  gateN<0x0F, N>(s, K + 0*6  + base, pm[0],  lane4);
  gateN<0x1E, N>(s, K + 1*6  + base, pm[1],  lane4);
  gateN<0x3C, N>(s, K + 2*6  + base, pm[2],  lane4);
  gateN<0x3B, N>(s, K + 3*6  + base, pm[3],  lane4);
  gateN<0x3F, N>(s, K + 4*6  + base, pm[4],  lane4);
  gateN<0x3D, N>(s, K + 5*6  + base, pm[5],  lane4);
  gateN<0x16, N>(s, K + 6*6  + base, pm[6],  lane4);
  gateN<0x26, N>(s, K + 7*6  + base, pm[7],  lane4);
  gateN<0x05, N>(s, K + 8*6  + base, pm[8],  lane4);
  gateN<0x28, N>(s, K + 9*6  + base, pm[9],  lane4);
  gateN<0x14, N>(s, K + 10*6 + base, pm[10], lane4);
  gateN<0x0A, N>(s, K + 11*6 + base, pm[11], lane4);
}

// merged FWHT over N circuits + final indexed gather
template<int N>
__device__ __forceinline__ void expvalsN(const v2f (&s)[N], float (&Wv)[N],
                                         const float (&fs)[9], int lane4, int gaddr) {
  float p[N];
#pragma unroll
  for (int c = 0; c < N; ++c) p[c] = fmaf(s[c].x, s[c].x, s[c].y * s[c].y);
#pragma unroll
  for (int c = 0; c < N; ++c) {
    float pa = shx<1>(p[c], lane4), pb = shx<2>(p[c], lane4), pc = shx<3>(p[c], lane4);
    p[c] = fmaf(fs[0], p[c], fmaf(fs[1], pa, fmaf(fs[2], pb, pc)));
  }
#pragma unroll
  for (int c = 0; c < N; ++c) {
    float pa = shx<4>(p[c], lane4), pb = shx<8>(p[c], lane4), pc = shx<12>(p[c], lane4);
    p[c] = fmaf(fs[3], p[c], fmaf(fs[4], pa, fmaf(fs[5], pb, pc)));
  }
#pragma unroll
  for (int c = 0; c < N; ++c) {
    float pa = shx<16>(p[c], lane4), pb = shx<32>(p[c], lane4), pc = shx<48>(p[c], lane4);
    p[c] = fmaf(fs[6], p[c], fmaf(fs[7], pa, fmaf(fs[8], pb, pc)));
  }
#pragma unroll
  for (int c = 0; c < N; ++c)
    Wv[c] = __int_as_float(__builtin_amdgcn_ds_bpermute(gaddr, __float_as_int(p[c])));
}

// half-angle products for wire value Xv: A=c1c2 B=c1s2 C=s1c2 D=s1s2
__device__ __forceinline__ void trig(float Xv, float& A_, float& B_, float& C_, float& D_) {
  float tq   = Xv * Xv;
  float cth1 = rsqrtf(1.f + tq);
  float sth1 = Xv * cth1;
  float u1   = 1.f + cth1, r1 = rsqrtf(u1 + u1);
  float c1   = u1 * r1,    s1 = sth1 * r1;
  float tq2  = tq * tq;
  float cth2 = rsqrtf(1.f + tq2);
  float sth2 = tq * cth2;
  float u2   = 1.f + cth2, r2 = rsqrtf(u2 + u2);
  float c2   = u2 * r2,    s2 = sth2 * r2;
  A_ = c1 * c2; B_ = c1 * s2; C_ = s1 * c2; D_ = s1 * s2;
}

// product-state embedding via readlane broadcast (verified R2/R4-R6 form)
__device__ __forceinline__ v2f embed_rl(float A_, float B_, float C_, float D_, int lane) {
  float ar, ai;
  {
    float Aj = rl(A_,0), Bj = rl(B_,0), Cj = rl(C_,0), Dj = rl(D_,0);
    bool bj = lane & 1;
    ar = bj ? Cj : Aj;
    ai = bj ? Dj : -Bj;
  }
#pragma unroll
  for (int jj = 1; jj < 6; ++jj) {
    float Aj = rl(A_,jj), Bj = rl(B_,jj), Cj = rl(C_,jj), Dj = rl(D_,jj);
    bool bj = (lane >> jj) & 1;
    float fr = bj ? Cj : Aj;
    float fi = bj ? Dj : -Bj;
    float nr = ar * fr - ai * fi;
    ai = fmaf(ar, fi, ai * fr);
    ar = nr;
  }
  v2f s; s.x = ar; s.y = ai; return s;
}

#define PACK_IDX ((0x2AULL)|(0x15ULL<<6)|(0x01ULL<<12)|(0x35ULL<<18)|(0x3AULL<<24)|(0x3DULL<<30))

} // namespace

// ---- prep kernel: fuse RZ*RY*RX row-0 per (circuit,layer,wire) -> d_ws ----
__global__ void qlstm_prep(const float* __restrict__ phi, float4* __restrict__ Kw) {
  int k = threadIdx.x;
  if (k < 72) {
    int g = k / 12, rem = k % 12, l = rem / 6, i = rem % 6;
    const float* w = phi + g*36 + l*18 + i*3;
    float sa, ca, sb, cb, sc, cc;
    sincosf(0.5f * w[0], &sa, &ca);
    sincosf(0.5f * w[1], &sb, &cb);
    sincosf(0.5f * w[2], &sc, &cc);
    float m00r =  cb*ca, m00i =  sb*sa;
    float m01r = -sb*ca, m01i = -cb*sa;
    float4 A;
    A.x = m00r*cc + m00i*sc;  A.y = m00i*cc - m00r*sc;
    A.z = m01r*cc + m01i*sc;  A.w = m01i*cc - m01r*sc;
    Kw[rem*6 + g] = A;   // layout [gate][circuit]
  }
}

__global__ __launch_bounds__(64) __attribute__((amdgpu_waves_per_eu(1)))
void qlstm_kernel(const float* __restrict__ x, const float* __restrict__ Wc,
                  const float* __restrict__ bc, const float4* __restrict__ Kw,
                  float* __restrict__ out)
{
  const int lane  = threadIdx.x & 63;
  const int lane4 = lane << 2;
  const int b     = blockIdx.x;

  // ---- per-lane loop-invariants ----
  const int j = (lane < 6) ? lane : 0;           // owned wire
  float Wr[14];
#pragma unroll
  for (int k = 0; k < 14; ++k) Wr[k] = Wc[j*14 + k];
  const float bcj = bc[j];

  float sgn[6];
#pragma unroll
  for (int k = 0; k < 6; ++k) sgn[k] = ((lane >> k) & 1) ? -1.f : 1.f;
  float fs[9] = { sgn[0]*sgn[1], sgn[1], sgn[0],
                  sgn[2]*sgn[3], sgn[3], sgn[2],
                  sgn[4]*sgn[5], sgn[5], sgn[4] };

  int sh    = (lane < 6) ? (6 * lane) : 0;
  int gaddr = (int)((PACK_IDX >> sh) & 63ULL) << 2;

  constexpr unsigned BM[2][6] = {
    {0x18,0x30,0x39,0x0C,0x26,0x33},
    {0x2A,0x15,0x01,0x35,0x3A,0x3D}};
  int pm[12];
#pragma unroll
  for (int l = 0; l < 2; ++l)
#pragma unroll
    for (int i = 0; i < 6; ++i)
      pm[l*6+i] = (__popc(lane & (int)BM[l][i]) & 1) << 31;

  float c_sc = 0.f;   // lane i (<6) owns c_i
  float hreg = 0.f;   // lane i (<6) owns h_i

  const float* xbase = x + (size_t)b * TSTEPS * 8;
  float4 xa = *(const float4*)(xbase);
  float4 xb = *(const float4*)(xbase + 4);

  const float4* kp = Kw;

  for (int t = 0; t < TSTEPS; ++t) {
    // defeat LICM of the 72 uniform coefficient loads (R6 spill root-cause)
    asm volatile("" : "+s"(kp));

    // ---- X_j in lane j (h via readlane; no cross-wave traffic) ----
    float h0 = rl(hreg,0), h1 = rl(hreg,1), h2 = rl(hreg,2);
    float h3 = rl(hreg,3), h4 = rl(hreg,4), h5 = rl(hreg,5);
    float acc = bcj;
    acc = fmaf(xa.x, Wr[0],  acc); acc = fmaf(xa.y, Wr[1],  acc);
    acc = fmaf(xa.z, Wr[2],  acc); acc = fmaf(xa.w, Wr[3],  acc);
    acc = fmaf(xb.x, Wr[4],  acc); acc = fmaf(xb.y, Wr[5],  acc);
    acc = fmaf(xb.z, Wr[6],  acc); acc = fmaf(xb.w, Wr[7],  acc);
    acc = fmaf(h0,   Wr[8],  acc); acc = fmaf(h1,   Wr[9],  acc);
    acc = fmaf(h2,   Wr[10], acc); acc = fmaf(h3,   Wr[11], acc);
    acc = fmaf(h4,   Wr[12], acc); acc = fmaf(h5,   Wr[13], acc);
    float Xj = 1.f - 2.f / (1.f + __expf(acc));

    // prefetch next x (in flight across the whole step)
    int tn = (t + 1 < TSTEPS) ? (t + 1) : t;
    float4 xa_n = *(const float4*)(xbase + (size_t)tn * 8);
    float4 xb_n = *(const float4*)(xbase + (size_t)tn * 8 + 4);

    // ---- phase 1: ONE embed, 4 interleaved circuits (f,i,C,o) ----
    float A_, B_, C_, D_;
    trig(Xj, A_, B_, C_, D_);
    v2f e = embed_rl(A_, B_, C_, D_, lane);
    v2f s4[4] = { e, e, e, e };
    chainN<4>(s4, kp, 0, pm, lane4);
    float Wv[4];
    expvalsN<4>(s4, Wv, fs, lane4, gaddr);

    // ---- cell update (per-lane, lanes 0-5 meaningful) ----
    float fg = sigf(Wv[0]), ig = sigf(Wv[1]);
    float Cg = sigf(Wv[2]), og = sigf(Wv[3]);
    float cn = fmaf(fg, c_sc, ig * Cg);
    c_sc = cn;
    float resc = og * tanh_fast(cn);

    // ---- phase 2: ONE embed, 2 interleaved circuits (h, y) ----
    float A2, B2, C2, D2;
    trig(resc, A2, B2, C2, D2);
    v2f e2 = embed_rl(A2, B2, C2, D2, lane);
    v2f s2[2] = { e2, e2 };
    chainN<2>(s2, kp, 4, pm, lane4);
    float Wv2[2];
    expvalsN<2>(s2, Wv2, fs, lane4, gaddr);

    hreg = Wv2[0];
    if (lane < 6) out[((size_t)b * TSTEPS + t) * 6 + lane] = Wv2[1];

    xa = xa_n; xb = xb_n;
  }

  // ---- final c, h ----
  if (lane < 6) {
    size_t cbase = (size_t)BATCH * TSTEPS * 6;
    out[cbase + (size_t)b * 6 + lane] = c_sc;
    out[cbase + (size_t)BATCH * 6 + (size_t)b * 6 + lane] = hreg;
  }
}

extern "C" void kernel_launch(void* const* d_in, const int* in_sizes, int n_in,
                              void* d_out, int out_size, void* d_ws, size_t ws_size,
                              hipStream_t stream) {
  const float* x   = (const float*)d_in[0];
  const float* phi = (const float*)d_in[1];
  const float* Wc  = (const float*)d_in[2];
  const float* bc  = (const float*)d_in[3];
  float* out = (float*)d_out;
  float4* Kw = (float4*)d_ws;   // 72 float4 = 1152 B
  (void)in_sizes; (void)n_in; (void)out_size; (void)ws_size;
  hipLaunchKernelGGL(qlstm_prep, dim3(1), dim3(128), 0, stream, phi, Kw);
  hipLaunchKernelGGL(qlstm_kernel, dim3(BATCH), dim3(64), 0, stream,
                     x, Wc, bc, Kw, out);
}

// Round 8
// 644.492 us; speedup vs baseline: 3.0991x; 1.8354x over previous
//
#include <hip/hip_runtime.h>

// Quantum-LSTM forward. 512 blocks x 4 waves, 1 sample/block (R5 structure,
// best measured base). Round-8 fixes the two diagnosed leaks of the 620us
// plateau:
//  1. Coefficient VGPR residency enforced with IN-LOOP asm pins: R3/R5
//     pinned once before the loop and the compiler still rematerialized
//     LDS reads inside (VGPR=124 < pinned set). Pinning at every iteration
//     top makes remat profitless -- the values must be in VGPRs at each
//     loop boundary anyway. waves_per_eu(2,2) gives the 256-VGPR budget.
//  2. Raw `s_waitcnt lgkmcnt(0); s_barrier` instead of __syncthreads():
//     only DS visibility is needed (gates4 / h_s); the full vmcnt drain of
//     __syncthreads killed the x-prefetch twice per step.
// Everything else (12-gate uniform-coeff chains via SU(2) conj-neg, DPP
// shuffle set, readlane embed, merged FWHT) is bit-identical to R5 (passed).

namespace {

constexpr int BATCH  = 512;
constexpr int TSTEPS = 256;

typedef float v2f __attribute__((ext_vector_type(2)));

__device__ __forceinline__ v2f splat2(float s) { v2f r; r.x = s; r.y = s; return r; }
__device__ __forceinline__ v2f cswapneg(v2f v) { v2f r; r.x = -v.y; r.y = v.x; return r; }

__device__ __forceinline__ float sigf(float v) { return 1.0f / (1.0f + __expf(-v)); }
__device__ __forceinline__ float tanh_fast(float v) { return 1.0f - 2.0f / (1.0f + __expf(v + v)); }

__device__ __forceinline__ float rl(float v, int l) {
  return __int_as_float(__builtin_amdgcn_readlane(__float_as_int(v), l));
}

template<int CTRL>
__device__ __forceinline__ float dppmov(float v) {
  return __int_as_float(__builtin_amdgcn_mov_dpp(__float_as_int(v), CTRL, 0xF, 0xF, true));
}
// Verified (R4-R7): quad_perm xor1=0xB1 xor2=0x4E xor3=0x1B; half_mirror=0x141
// (xor7), row_ror:8=0x128 (xor8), row_mirror=0x140 (xorF); composites 4,5,A,C.

template<int M>
__device__ __forceinline__ float shx(float v, int lane4) {
  if constexpr      (M == 0x01) return dppmov<0xB1>(v);
  else if constexpr (M == 0x02) return dppmov<0x4E>(v);
  else if constexpr (M == 0x03) return dppmov<0x1B>(v);
  else if constexpr (M == 0x04) return dppmov<0x1B>(dppmov<0x141>(v));
  else if constexpr (M == 0x05) return dppmov<0x4E>(dppmov<0x141>(v));
  else if constexpr (M == 0x07) return dppmov<0x141>(v);
  else if constexpr (M == 0x08) return dppmov<0x128>(v);
  else if constexpr (M == 0x0A) return dppmov<0x4E>(dppmov<0x128>(v));
  else if constexpr (M == 0x0C) return dppmov<0x1B>(dppmov<0x140>(v));
  else if constexpr (M == 0x0F) return dppmov<0x140>(v);
  else if constexpr (M < 32) {
    return __int_as_float(__builtin_amdgcn_ds_swizzle(__float_as_int(v), 0x1F | (M << 10)));
  } else {
    return __int_as_float(__builtin_amdgcn_ds_bpermute(lane4 ^ (M << 2), __float_as_int(v)));
  }
}

// one gate: uniform coeffs A=(G00r,G00i,G01r,G01i), per-lane sign mask pm
// (0 or 0x80000000). Row select == conj-neg (SU(2)).
template<int M>
__device__ __forceinline__ void gate1(v2f& s, float4 A, int pm, int lane4) {
  v2f v; v.x = shx<M>(s.x, lane4); v.y = shx<M>(s.y, lane4);
  float sai = __int_as_float(__float_as_int(A.y) ^ pm);
  float sbr = __int_as_float(__float_as_int(A.z) ^ pm);
  v2f u = splat2(A.x) * s;
  u = __builtin_elementwise_fma(splat2(sai), cswapneg(s), u);
  u = __builtin_elementwise_fma(splat2(sbr), v,           u);
  u = __builtin_elementwise_fma(splat2(A.w), cswapneg(v), u);
  s = u;
}

__device__ __forceinline__ void gate_chain(v2f& s, const float4 (&CA)[12],
                                           const int (&pm)[12], int lane4) {
  gate1<0x0F>(s, CA[0],  pm[0],  lane4);
  gate1<0x1E>(s, CA[1],  pm[1],  lane4);
  gate1<0x3C>(s, CA[2],  pm[2],  lane4);
  gate1<0x3B>(s, CA[3],  pm[3],  lane4);
  gate1<0x3F>(s, CA[4],  pm[4],  lane4);
  gate1<0x3D>(s, CA[5],  pm[5],  lane4);
  gate1<0x16>(s, CA[6],  pm[6],  lane4);
  gate1<0x26>(s, CA[7],  pm[7],  lane4);
  gate1<0x05>(s, CA[8],  pm[8],  lane4);
  gate1<0x28>(s, CA[9],  pm[9],  lane4);
  gate1<0x14>(s, CA[10], pm[10], lane4);
  gate1<0x0A>(s, CA[11], pm[11], lane4);
}

// merged FWHT + final gather
__device__ __forceinline__ float expvals(v2f s, const float (&fs)[9],
                                         int lane4, int gaddr) {
  float p  = fmaf(s.x, s.x, s.y * s.y);
  float pa = shx<1>(p, lane4), pb = shx<2>(p, lane4), pc = shx<3>(p, lane4);
  p = fmaf(fs[0], p, fmaf(fs[1], pa, fmaf(fs[2], pb, pc)));
  pa = shx<4>(p, lane4); pb = shx<8>(p, lane4); pc = shx<12>(p, lane4);
  p = fmaf(fs[3], p, fmaf(fs[4], pa, fmaf(fs[5], pb, pc)));
  pa = shx<16>(p, lane4); pb = shx<32>(p, lane4); pc = shx<48>(p, lane4);
  p = fmaf(fs[6], p, fmaf(fs[7], pa, fmaf(fs[8], pb, pc)));
  return __int_as_float(__builtin_amdgcn_ds_bpermute(gaddr, __float_as_int(p)));
}

// half-angle products for wire value Xv: A=c1c2 B=c1s2 C=s1c2 D=s1s2
__device__ __forceinline__ void trig(float Xv, float& A_, float& B_, float& C_, float& D_) {
  float tq   = Xv * Xv;
  float cth1 = rsqrtf(1.f + tq);
  float sth1 = Xv * cth1;
  float u1   = 1.f + cth1, r1 = rsqrtf(u1 + u1);
  float c1   = u1 * r1,    s1 = sth1 * r1;
  float tq2  = tq * tq;
  float cth2 = rsqrtf(1.f + tq2);
  float sth2 = tq * cth2;
  float u2   = 1.f + cth2, r2 = rsqrtf(u2 + u2);
  float c2   = u2 * r2,    s2 = sth2 * r2;
  A_ = c1 * c2; B_ = c1 * s2; C_ = s1 * c2; D_ = s1 * s2;
}

// product-state embedding via readlane broadcast (verified R2/R4-R7 form)
__device__ __forceinline__ v2f embed_rl(float A_, float B_, float C_, float D_, int lane) {
  float ar, ai;
  {
    float Aj = rl(A_,0), Bj = rl(B_,0), Cj = rl(C_,0), Dj = rl(D_,0);
    bool bj = lane & 1;
    ar = bj ? Cj : Aj;
    ai = bj ? Dj : -Bj;
  }
#pragma unroll
  for (int jj = 1; jj < 6; ++jj) {
    float Aj = rl(A_,jj), Bj = rl(B_,jj), Cj = rl(C_,jj), Dj = rl(D_,jj);
    bool bj = (lane >> jj) & 1;
    float fr = bj ? Cj : Aj;
    float fi = bj ? Dj : -Bj;
    float nr = ar * fr - ai * fi;
    ai = fmaf(ar, fi, ai * fr);
    ar = nr;
  }
  v2f s; s.x = ar; s.y = ai; return s;
}

#define PACK_IDX ((0x2AULL)|(0x15ULL<<6)|(0x01ULL<<12)|(0x35ULL<<18)|(0x3AULL<<24)|(0x3DULL<<30))
#define PIN4(v) asm volatile("" : "+v"((v).x), "+v"((v).y), "+v"((v).z), "+v"((v).w))
// DS-only barrier: orders LDS (lgkmcnt) but leaves global prefetch in flight
#define BARRIER_DS() asm volatile("s_waitcnt lgkmcnt(0)\ns_barrier" ::: "memory")

} // namespace

__global__ __attribute__((amdgpu_flat_work_group_size(256, 256)))
           __attribute__((amdgpu_waves_per_eu(2, 2)))
void qlstm_kernel(const float* __restrict__ x, const float* __restrict__ phi,
                  const float* __restrict__ Wc, const float* __restrict__ bc,
                  float* __restrict__ out)
{
  __shared__ float4 fG[72];        // 6 circuits x 12 gates, row0 only (G00,G01)
  __shared__ float4 gates4[6];     // per-wire (f,i,C,o), sigmoided
  __shared__ __align__(16) float h_s[8];

  const int tid   = threadIdx.x;
  const int wave  = tid >> 6;
  const int lane  = tid & 63;
  const int lane4 = lane << 2;
  const int b     = blockIdx.x;

  // ---- one-time: fused gate row0 per (circuit,layer,wire) ----
  if (tid < 72) {
    int g = tid / 12, rem = tid % 12, l = rem / 6, i = rem % 6;
    const float* w = phi + g*36 + l*18 + i*3;
    float sa, ca, sb, cb, sc, cc;
    sincosf(0.5f * w[0], &sa, &ca);
    sincosf(0.5f * w[1], &sb, &cb);
    sincosf(0.5f * w[2], &sc, &cc);
    float m00r =  cb*ca, m00i =  sb*sa;
    float m01r = -sb*ca, m01i = -cb*sa;
    float4 A;
    A.x = m00r*cc + m00i*sc;  A.y = m00i*cc - m00r*sc;
    A.z = m01r*cc + m01i*sc;  A.w = m01i*cc - m01r*sc;
    fG[tid] = A;
  }
  if (tid < 8) h_s[tid] = 0.f;
  __syncthreads();

  // ---- per-wave/lane loop-invariants ----
  const int j = (lane < 6) ? lane : 0;           // owned wire
  float Wr[14];
#pragma unroll
  for (int k = 0; k < 14; ++k) Wr[k] = Wc[j*14 + k];
  const float bcj = bc[j];

  float sgn[6];
#pragma unroll
  for (int k = 0; k < 6; ++k) sgn[k] = ((lane >> k) & 1) ? -1.f : 1.f;
  float fs[9] = { sgn[0]*sgn[1], sgn[1], sgn[0],
                  sgn[2]*sgn[3], sgn[3], sgn[2],
                  sgn[4]*sgn[5], sgn[5], sgn[4] };

  int sh    = (lane < 6) ? (6 * lane) : 0;
  int gaddr = (int)((PACK_IDX >> sh) & 63ULL) << 2;

  // per-lane sign masks (gate order), circuit-independent
  constexpr unsigned BM[2][6] = {
    {0x18,0x30,0x39,0x0C,0x26,0x33},
    {0x2A,0x15,0x01,0x35,0x3A,0x3D}};
  int pm[12];
#pragma unroll
  for (int l = 0; l < 2; ++l)
#pragma unroll
    for (int i = 0; i < 6; ++i)
      pm[l*6+i] = (__popc(lane & (int)BM[l][i]) & 1) << 31;

  // uniform coefficient sets: phase-1 circuit (wave) and phase-2 (4+wave&1)
  float4 CA1[12], CA2[12];
#pragma unroll
  for (int i = 0; i < 12; ++i) {
    CA1[i] = fG[wave * 12 + i];
    CA2[i] = fG[(4 + (wave & 1)) * 12 + i];
  }

  float c_sc  = 0.f;   // lane i (<6) of waves 0,1 owns c_i
  float hlast = 0.f;

  const float* xbase = x + (size_t)b * TSTEPS * 8;
  float4 xa = *(const float4*)(xbase);
  float4 xb = *(const float4*)(xbase + 4);

  for (int t = 0; t < TSTEPS; ++t) {
    // residency enforcement: all coefficients must be live VGPRs at every
    // iteration boundary -> rematerializing LDS reads is never profitable
#pragma unroll
    for (int i = 0; i < 12; ++i) { PIN4(CA1[i]); PIN4(CA2[i]); }
#pragma unroll
    for (int k = 0; k < 14; ++k) asm volatile("" : "+v"(Wr[k]));

    // ---- phase 1: X_j in lane j, embed, circuit (f,i,C,o per wave) ----
    float4 h4 = *(const float4*)&h_s[0];
    float2 h2 = *(const float2*)&h_s[4];
    float acc = bcj;
    acc = fmaf(xa.x, Wr[0],  acc); acc = fmaf(xa.y, Wr[1],  acc);
    acc = fmaf(xa.z, Wr[2],  acc); acc = fmaf(xa.w, Wr[3],  acc);
    acc = fmaf(xb.x, Wr[4],  acc); acc = fmaf(xb.y, Wr[5],  acc);
    acc = fmaf(xb.z, Wr[6],  acc); acc = fmaf(xb.w, Wr[7],  acc);
    acc = fmaf(h4.x, Wr[8],  acc); acc = fmaf(h4.y, Wr[9],  acc);
    acc = fmaf(h4.z, Wr[10], acc); acc = fmaf(h4.w, Wr[11], acc);
    acc = fmaf(h2.x, Wr[12], acc); acc = fmaf(h2.y, Wr[13], acc);
    float Xj = 1.f - 2.f / (1.f + __expf(acc));

    // prefetch next x -- stays in flight across the raw barriers
    int tn = (t + 1 < TSTEPS) ? (t + 1) : t;
    float4 xa_n = *(const float4*)(xbase + (size_t)tn * 8);
    float4 xb_n = *(const float4*)(xbase + (size_t)tn * 8 + 4);

    float A_, B_, C_, D_;
    trig(Xj, A_, B_, C_, D_);
    v2f s = embed_rl(A_, B_, C_, D_, lane);
    gate_chain(s, CA1, pm, lane4);
    float Wv  = expvals(s, fs, lane4, gaddr);
    float sgv = sigf(Wv);
    if (lane < 6) ((float*)&gates4[lane])[wave] = sgv;
    BARRIER_DS();

    // ---- phase 2: cell update + circuits h (wave0), y (wave1) ----
    if (wave < 2) {
      float4 g4 = gates4[j];                       // (f,i,C,o) for wire j
      float cn  = fmaf(g4.x, c_sc, g4.y * g4.z);
      c_sc = cn;
      float resc = g4.w * tanh_fast(cn);
      float A2, B2, C2, D2;
      trig(resc, A2, B2, C2, D2);
      v2f s2 = embed_rl(A2, B2, C2, D2, lane);
      gate_chain(s2, CA2, pm, lane4);
      float Wv2 = expvals(s2, fs, lane4, gaddr);
      if (wave == 0) {
        if (lane < 6) h_s[lane] = Wv2;
        hlast = Wv2;
      } else if (lane < 6) {
        out[((size_t)b * TSTEPS + t) * 6 + lane] = Wv2;
      }
    }
    xa = xa_n; xb = xb_n;
    BARRIER_DS();
  }

  // ---- final c, h ----
  if (wave == 0 && lane < 6) {
    size_t cbase = (size_t)BATCH * TSTEPS * 6;
    out[cbase + (size_t)b * 6 + lane] = c_sc;
    out[cbase + (size_t)BATCH * 6 + (size_t)b * 6 + lane] = hlast;
  }
}

extern "C" void kernel_launch(void* const* d_in, const int* in_sizes, int n_in,
                              void* d_out, int out_size, void* d_ws, size_t ws_size,
                              hipStream_t stream) {
  const float* x   = (const float*)d_in[0];
  const float* phi = (const float*)d_in[1];
  const float* Wc  = (const float*)d_in[2];
  const float* bc  = (const float*)d_in[3];
  float* out = (float*)d_out;
  (void)in_sizes; (void)n_in; (void)out_size; (void)d_ws; (void)ws_size;
  hipLaunchKernelGGL(qlstm_kernel, dim3(BATCH), dim3(256), 0, stream,
                     x, phi, Wc, bc, out);
}